// Round 5
// baseline (340.328 us; speedup 1.0000x reference)
//
#include <hip/hip_runtime.h>
#include <stdint.h>

// ---------------- common types / helpers ----------------
using bf16x8 = __attribute__((ext_vector_type(8))) short;   // 8 bf16 (4 VGPRs)
using f32x4  = __attribute__((ext_vector_type(4))) float;
using f32x2  = __attribute__((ext_vector_type(2))) float;
using u16    = unsigned short;
using u16x4  = __attribute__((ext_vector_type(4))) unsigned short;
using u16x8  = __attribute__((ext_vector_type(8))) unsigned short;
using bf16x2v = __attribute__((ext_vector_type(2))) __bf16;

#define LOG2E 1.4426950408889634f

static __device__ __forceinline__ u16 bf16r(float f) {
  union { __bf16 h; u16 u; } v; v.h = (__bf16)f; return v.u;
}
static __device__ __forceinline__ unsigned pk2(float a, float b) {
  union { bf16x2v h; unsigned u; } r;
  r.h = __builtin_convertvector((f32x2){a, b}, bf16x2v);
  return r.u;
}
static __device__ __forceinline__ u16x4 pk4(float a, float b, float c, float d) {
  union { unsigned u[2]; u16x4 v; } r;
  r.u[0] = pk2(a, b); r.u[1] = pk2(c, d);
  return r.v;
}

static __device__ __forceinline__ void async_ld16(u16* lds, const u16* g) {
  __builtin_amdgcn_global_load_lds(
      (const __attribute__((address_space(1))) void*)g,
      (__attribute__((address_space(3))) void*)lds,
      16, 0, 0);
}

static __device__ __forceinline__ f32x4 mfma16(bf16x8 a, bf16x8 b, f32x4 c) {
  return __builtin_amdgcn_mfma_f32_16x16x32_bf16(a, b, c, 0, 0, 0);
}

// ---------------- kernel 1: fused prep (casts + weight transposes) ----------------
__global__ void prep_kernel(const float* __restrict__ x, const float* __restrict__ ctx,
                            const float* __restrict__ W0, const float* __restrict__ W1,
                            const float* __restrict__ W2, const float* __restrict__ W3,
                            u16* __restrict__ Xb, u16* __restrict__ Cb,
                            u16* __restrict__ T0, u16* __restrict__ T1,
                            u16* __restrict__ T2, u16* __restrict__ T3) {
  int bid = blockIdx.x;
  int t = threadIdx.x;
  if (bid < 4096) {
    const int n4 = 2097152;                       // float4s per tensor
    int i = bid * 256 + t;
    const int stride = 4096 * 256;
#pragma unroll
    for (int it = 0; it < 4; ++it, i += stride) {
      const float4* src = (i < n4) ? ((const float4*)x + i) : ((const float4*)ctx + (i - n4));
      u16x4* dst = (i < n4) ? ((u16x4*)Xb + i) : ((u16x4*)Cb + (i - n4));
      float4 v = *src;
      *dst = pk4(v.x, v.y, v.z, v.w);
    }
    return;
  }
  int b2 = bid - 4096;
  int z = b2 >> 8, rem = b2 & 255;
  const float* W = (z == 0) ? W0 : (z == 1) ? W1 : (z == 2) ? W2 : W3;
  u16* T = (z == 0) ? T0 : (z == 1) ? T1 : (z == 2) ? T2 : T3;
  __shared__ float tile[64][65];
  int k0 = (rem & 15) * 64, n0 = (rem >> 4) * 64;
#pragma unroll
  for (int i = 0; i < 4; ++i) {
    int kl = i * 16 + (t >> 4); int nl = (t & 15) * 4;
    float4 v = *(const float4*)(W + (size_t)(k0 + kl) * 1024 + n0 + nl);
    tile[kl][nl] = v.x; tile[kl][nl + 1] = v.y; tile[kl][nl + 2] = v.z; tile[kl][nl + 3] = v.w;
  }
  __syncthreads();
#pragma unroll
  for (int i = 0; i < 16; ++i) {
    int idx = i * 256 + t; int nl = idx >> 6; int kl = idx & 63;
    T[(size_t)(n0 + nl) * 1024 + k0 + kl] = bf16r(tile[kl][nl]);
  }
}

// ---------------- kernel 2: QKV projection GEMM (128x128 tile, dbuf LDS, counted vmcnt) ----------------
__global__ __launch_bounds__(256, 2) void proj_gemm_kernel(
    const u16* __restrict__ Xb, const u16* __restrict__ Cb,
    const u16* __restrict__ Wqt, const u16* __restrict__ Wkt, const u16* __restrict__ Wvt,
    const float* __restrict__ bq, const float* __restrict__ bk, const float* __restrict__ bv,
    u16* __restrict__ Qo, u16* __restrict__ Ko, u16* __restrict__ Vo) {
  __shared__ u16 smem[32768];           // A dbuf 2x[128][64] @0, B dbuf 2x[128][64] @16384  (64 KB)
  u16* sA = smem;
  u16* sB = smem + 16384;
  int z = blockIdx.z;
  const u16* A    = (z == 0) ? Xb : Cb;
  const u16* Bt   = (z == 0) ? Wqt : (z == 1) ? Wkt : Wvt;
  const float* bias = (z == 0) ? bq : (z == 1) ? bk : bv;
  int m0 = blockIdx.x * 128, n0 = blockIdx.y * 128;
  int t = threadIdx.x, w = t >> 6, lane = t & 63, quad = lane >> 4, lc = lane & 15;
  int wm = (w & 1) * 64, wn = (w >> 1) * 64;
  int sx = lc & 7;

  f32x4 acc[4][4];
  f32x4 z4 = {0.f, 0.f, 0.f, 0.f};
#pragma unroll
  for (int i = 0; i < 4; ++i)
#pragma unroll
    for (int j = 0; j < 4; ++j) acc[i][j] = z4;

  const u16* Abase = A  + (size_t)m0 * 1024;
  const u16* Bbase = Bt + (size_t)n0 * 1024;

  auto STAGE = [&](int s, int kt) {
#pragma unroll
    for (int i = 0; i < 4; ++i) {                 // A: 128 rows x 64 cols
      int c = i * 256 + t; int row = c >> 3; int cc = c & 7;
      async_ld16(sA + s * 8192 + c * 8,
                 Abase + (size_t)row * 1024 + kt * 64 + ((cc ^ (row & 7)) * 8));
    }
#pragma unroll
    for (int i = 0; i < 4; ++i) {                 // B: 128 rows x 64 cols
      int c = i * 256 + t; int row = c >> 3; int cc = c & 7;
      async_ld16(sB + s * 8192 + c * 8,
                 Bbase + (size_t)row * 1024 + kt * 64 + ((cc ^ (row & 7)) * 8));
    }
  };

  STAGE(0, 0);
  STAGE(1, 1);

  for (int kt = 0; kt < 16; ++kt) {
    int s = kt & 1;
    if (kt < 15) asm volatile("s_waitcnt vmcnt(8)" ::: "memory");   // tile kt landed; kt+1 in flight
    else         asm volatile("s_waitcnt vmcnt(0)" ::: "memory");
    __builtin_amdgcn_s_barrier();
    const u16* pA = sA + s * 8192;
    const u16* pB = sB + s * 8192;
#pragma unroll
    for (int ks = 0; ks < 2; ++ks) {
      bf16x8 af[4], bfr[4];
#pragma unroll
      for (int i = 0; i < 4; ++i)
        af[i]  = *(const bf16x8*)(pA + (wm + i * 16 + lc) * 64 + (((ks * 4 + quad) ^ sx)) * 8);
#pragma unroll
      for (int i = 0; i < 4; ++i)
        bfr[i] = *(const bf16x8*)(pB + (wn + i * 16 + lc) * 64 + (((ks * 4 + quad) ^ sx)) * 8);
      __builtin_amdgcn_s_setprio(1);
#pragma unroll
      for (int qi = 0; qi < 4; ++qi)
#pragma unroll
        for (int nj = 0; nj < 4; ++nj) acc[qi][nj] = mfma16(af[qi], bfr[nj], acc[qi][nj]);
      __builtin_amdgcn_s_setprio(0);
    }
    __builtin_amdgcn_s_barrier();                 // all waves done reading slot s
    if (kt < 14) STAGE(s, kt + 2);                // overwrite freed slot, 1 tile ahead
  }

  if (z < 2) {
    u16* dst = (z == 0) ? Qo : Ko;
    float scl = (z == 0) ? 0.125f * LOG2E : 1.0f;   // fold softmax scale + log2e into Q
#pragma unroll
    for (int qi = 0; qi < 4; ++qi)
#pragma unroll
      for (int nj = 0; nj < 4; ++nj) {
        int n = n0 + wn + nj * 16 + lc;
        float bvv = bias[n];
        int hh = n >> 6, d = n & 63;
#pragma unroll
        for (int r = 0; r < 4; ++r) {
          int m = m0 + wm + qi * 16 + quad * 4 + r;
          int bb = m >> 10, pos = m & 1023;
          float v = (acc[qi][nj][r] + bvv) * scl;
          dst[((size_t)(bb * 16 + hh) * 1024 + pos) * 64 + d] = bf16r(v);
        }
      }
  } else {
    // V: write transposed [B,H,64,NKV] via per-wave LDS transpose
    __syncthreads();                      // all waves done with staging LDS
    u16* Tw = smem + w * (64 * 66);
    int hh = (n0 + wn) >> 6;
    int mb = m0 + wm; int bb = mb >> 10; int pos0 = mb & 1023;
#pragma unroll
    for (int qi = 0; qi < 4; ++qi)
#pragma unroll
      for (int nj = 0; nj < 4; ++nj) {
        int lcc = nj * 16 + lc;
        float bvv = bias[n0 + wn + lcc];
#pragma unroll
        for (int r = 0; r < 4; ++r) {
          int lr = qi * 16 + quad * 4 + r;
          Tw[lr * 66 + lcc] = bf16r(acc[qi][nj][r] + bvv);
        }
      }
#pragma unroll
    for (int i = 0; i < 8; ++i) {
      int dl = i * 8 + (lane >> 3); int kv0 = (lane & 7) * 8;
      u16x8 pk;
#pragma unroll
      for (int j = 0; j < 8; ++j) pk[j] = Tw[(kv0 + j) * 66 + dl];
      *(u16x8*)(Vo + ((size_t)(bb * 16 + hh) * 64 + dl) * 1024 + pos0 + kv0) = pk;
    }
  }
}

// ---------------- kernel 3: flash attention (kv-tile=64, single-buffer + split staging, 5 blocks/CU) ----------------
__global__ __launch_bounds__(256, 5) void attn_kernel(const u16* __restrict__ Qb,
                                                      const u16* __restrict__ Kb,
                                                      const u16* __restrict__ Vt,
                                                      u16* __restrict__ Ab) {
  // layout (u16 units): K@0 (4096), V@4096 (4096), P@8192 (8192)  = 32 KB
  __shared__ u16 smem[16384];
  u16* sK = smem;
  u16* sV = smem + 4096;
  u16* sP = smem + 8192;          // 8192 u16 [128q][64kv] swizzled
  int bid = blockIdx.x;
  int bh = (bid & 7) | ((bid >> 6) << 3);   // XCD-local K/V reuse
  int qt = (bid >> 3) & 7;
  int bb = bh >> 4, hh = bh & 15;
  int t = threadIdx.x, w = t >> 6, lane = t & 63, quad = lane >> 4, lc = lane & 15;

  const u16* Qg = Qb + ((size_t)bh * 1024 + qt * 128 + w * 32) * 64;
  bf16x8 qf[2][2];
#pragma unroll
  for (int qi = 0; qi < 2; ++qi)
#pragma unroll
    for (int ks = 0; ks < 2; ++ks)
      qf[qi][ks] = *(const bf16x8*)(Qg + (qi * 16 + lc) * 64 + ks * 32 + quad * 8);

  f32x4 O[4][2];
  f32x4 z4 = {0.f, 0.f, 0.f, 0.f};
#pragma unroll
  for (int dj = 0; dj < 4; ++dj) { O[dj][0] = z4; O[dj][1] = z4; }
  float l_lane[2] = {0.f, 0.f};

  const u16* Kg = Kb + (size_t)bh * 65536;
  const u16* Vg = Vt + (size_t)bh * 65536;
  int r0 = t >> 3, gs = t & 7;

  auto STAGE_K = [&](int kt) {
#pragma unroll
    for (int i = 0; i < 2; ++i) {
      int r = r0 + i * 32;
      async_ld16(sK + i * 2048 + t * 8, Kg + (size_t)(kt * 64 + r) * 64 + (gs ^ (r & 7)) * 8);
    }
  };
  auto STAGE_V = [&](int kt) {
#pragma unroll
    for (int i = 0; i < 2; ++i) {
      int d = r0 + i * 32;
      async_ld16(sV + i * 2048 + t * 8, Vg + (size_t)d * 1024 + kt * 64 + (gs ^ (d & 7)) * 8);
    }
  };

  STAGE_K(0);                                    // 2 loads in flight (oldest)
  STAGE_V(0);                                    // +2

  for (int kt = 0; kt < 16; ++kt) {
    // wait own K loads (FIFO: K issued before V); V may still be in flight
    asm volatile("s_waitcnt vmcnt(2)" ::: "memory");
    __builtin_amdgcn_s_barrier();                // all waves' K[kt] landed

    f32x4 s[4][2];
#pragma unroll
    for (int kj = 0; kj < 4; ++kj) { s[kj][0] = z4; s[kj][1] = z4; }
    __builtin_amdgcn_s_setprio(1);
#pragma unroll
    for (int kj = 0; kj < 4; ++kj) {
      int kv = kj * 16 + lc;
#pragma unroll
      for (int ks = 0; ks < 2; ++ks) {
        bf16x8 a = *(const bf16x8*)(sK + kv * 64 + ((ks * 4 + quad) ^ (kv & 7)) * 8);
        s[kj][0] = mfma16(a, qf[0][ks], s[kj][0]);
        s[kj][1] = mfma16(a, qf[1][ks], s[kj][1]);
      }
    }
    __builtin_amdgcn_s_setprio(0);

#pragma unroll
    for (int qi = 0; qi < 2; ++qi) {
      int q = w * 32 + qi * 16 + lc;
#pragma unroll
      for (int kj = 0; kj < 4; ++kj) {
        float p0 = exp2f(s[kj][qi][0]);
        float p1 = exp2f(s[kj][qi][1]);
        float p2 = exp2f(s[kj][qi][2]);
        float p3 = exp2f(s[kj][qi][3]);
        l_lane[qi] += (p0 + p1) + (p2 + p3);
        int g = kj * 2 + (quad >> 1);
        *(u16x4*)(sP + q * 64 + ((g ^ (q & 7)) * 8) + (quad & 1) * 4) = pk4(p0, p1, p2, p3);
      }
    }

    // wait own V loads; barrier => all waves' V landed AND all waves done with K reads
    asm volatile("s_waitcnt vmcnt(0)" ::: "memory");
    __builtin_amdgcn_s_barrier();
    if (kt < 15) STAGE_K(kt + 1);                // K slot free now; consumed next iter

    __builtin_amdgcn_s_setprio(1);
#pragma unroll
    for (int ks = 0; ks < 2; ++ks) {
      bf16x8 pb[2];
#pragma unroll
      for (int qi = 0; qi < 2; ++qi) {
        int q = w * 32 + qi * 16 + lc;
        pb[qi] = *(const bf16x8*)(sP + q * 64 + (((ks * 4 + quad) ^ (q & 7))) * 8);
      }
#pragma unroll
      for (int dj = 0; dj < 4; ++dj) {
        int d = dj * 16 + lc;
        bf16x8 va = *(const bf16x8*)(sV + d * 64 + (((ks * 4 + quad) ^ (d & 7))) * 8);
        O[dj][0] = mfma16(va, pb[0], O[dj][0]);
        O[dj][1] = mfma16(va, pb[1], O[dj][1]);
      }
    }
    __builtin_amdgcn_s_setprio(0);

    __builtin_amdgcn_s_barrier();                // all waves done with V reads
    if (kt < 15) STAGE_V(kt + 1);                // V slot free; consumed after next QK+softmax
  }

  float inv[2];
#pragma unroll
  for (int qi = 0; qi < 2; ++qi) {
    float l = l_lane[qi];
    l += __shfl_xor(l, 16);
    l += __shfl_xor(l, 32);
    inv[qi] = 1.f / l;
  }

  __syncthreads();
  u16* myP = smem + w * 2304;
#pragma unroll
  for (int qi = 0; qi < 2; ++qi)
#pragma unroll
    for (int dj = 0; dj < 4; ++dj)
      *(u16x4*)(myP + (qi * 16 + lc) * 72 + dj * 16 + quad * 4) =
          pk4(O[dj][qi][0] * inv[qi], O[dj][qi][1] * inv[qi],
              O[dj][qi][2] * inv[qi], O[dj][qi][3] * inv[qi]);
#pragma unroll
  for (int i = 0; i < 4; ++i) {
    int idx = i * 64 + lane; int ql = idx >> 3; int dg = idx & 7;
    u16x8 pk = *(const u16x8*)(myP + ql * 72 + dg * 8);
    *(u16x8*)(Ab + ((size_t)bb * 1024 + qt * 128 + w * 32 + ql) * 1024 + hh * 64 + dg * 8) = pk;
  }
}

// ---------------- kernel 4: output projection GEMM (128x128 tile, dbuf, counted vmcnt), fp32 out ----------------
__global__ __launch_bounds__(256, 2) void out_gemm_kernel(const u16* __restrict__ A,
                                                          const u16* __restrict__ Bt,
                                                          const float* __restrict__ bo,
                                                          float* __restrict__ out) {
  __shared__ u16 smem[32768];
  u16* sA = smem;
  u16* sB = smem + 16384;
  int m0 = blockIdx.x * 128, n0 = blockIdx.y * 128;
  int t = threadIdx.x, w = t >> 6, lane = t & 63, quad = lane >> 4, lc = lane & 15;
  int wm = (w & 1) * 64, wn = (w >> 1) * 64;
  int sx = lc & 7;
  f32x4 acc[4][4];
  f32x4 z4 = {0.f, 0.f, 0.f, 0.f};
#pragma unroll
  for (int i = 0; i < 4; ++i)
#pragma unroll
    for (int j = 0; j < 4; ++j) acc[i][j] = z4;

  const u16* Abase = A  + (size_t)m0 * 1024;
  const u16* Bbase = Bt + (size_t)n0 * 1024;

  auto STAGE = [&](int s, int kt) {
#pragma unroll
    for (int i = 0; i < 4; ++i) {
      int c = i * 256 + t; int row = c >> 3; int cc = c & 7;
      async_ld16(sA + s * 8192 + c * 8,
                 Abase + (size_t)row * 1024 + kt * 64 + ((cc ^ (row & 7)) * 8));
    }
#pragma unroll
    for (int i = 0; i < 4; ++i) {
      int c = i * 256 + t; int row = c >> 3; int cc = c & 7;
      async_ld16(sB + s * 8192 + c * 8,
                 Bbase + (size_t)row * 1024 + kt * 64 + ((cc ^ (row & 7)) * 8));
    }
  };

  STAGE(0, 0);
  STAGE(1, 1);

  for (int kt = 0; kt < 16; ++kt) {
    int s = kt & 1;
    if (kt < 15) asm volatile("s_waitcnt vmcnt(8)" ::: "memory");
    else         asm volatile("s_waitcnt vmcnt(0)" ::: "memory");
    __builtin_amdgcn_s_barrier();
    const u16* pA = sA + s * 8192;
    const u16* pB = sB + s * 8192;
#pragma unroll
    for (int ks = 0; ks < 2; ++ks) {
      bf16x8 af[4], bfr[4];
#pragma unroll
      for (int i = 0; i < 4; ++i)
        af[i]  = *(const bf16x8*)(pA + (wm + i * 16 + lc) * 64 + (((ks * 4 + quad) ^ sx)) * 8);
#pragma unroll
      for (int i = 0; i < 4; ++i)
        bfr[i] = *(const bf16x8*)(pB + (wn + i * 16 + lc) * 64 + (((ks * 4 + quad) ^ sx)) * 8);
      __builtin_amdgcn_s_setprio(1);
#pragma unroll
      for (int qi = 0; qi < 4; ++qi)
#pragma unroll
        for (int nj = 0; nj < 4; ++nj) acc[qi][nj] = mfma16(af[qi], bfr[nj], acc[qi][nj]);
      __builtin_amdgcn_s_setprio(0);
    }
    __builtin_amdgcn_s_barrier();
    if (kt < 14) STAGE(s, kt + 2);
  }

#pragma unroll
  for (int qi = 0; qi < 4; ++qi)
#pragma unroll
    for (int nj = 0; nj < 4; ++nj) {
      int n = n0 + wn + nj * 16 + lc;
      float bvv = bo[n];
#pragma unroll
      for (int r = 0; r < 4; ++r) {
        int m = m0 + wm + qi * 16 + quad * 4 + r;
        out[(size_t)m * 1024 + n] = acc[qi][nj][r] + bvv;
      }
    }
}

// ---------------- host ----------------
extern "C" void kernel_launch(void* const* d_in, const int* in_sizes, int n_in,
                              void* d_out, int out_size, void* d_ws, size_t ws_size,
                              hipStream_t stream) {
  const float* x   = (const float*)d_in[0];
  const float* ctx = (const float*)d_in[1];
  const float* Wq  = (const float*)d_in[2];
  const float* bq  = (const float*)d_in[3];
  const float* Wk  = (const float*)d_in[4];
  const float* bk  = (const float*)d_in[5];
  const float* Wv  = (const float*)d_in[6];
  const float* bv  = (const float*)d_in[7];
  const float* Wo  = (const float*)d_in[8];
  const float* bo  = (const float*)d_in[9];
  float* out = (float*)d_out;

  const size_t NE = (size_t)8192 * 1024;
  char* p = (char*)d_ws;
  u16* Xb  = (u16*)p;             p += NE * 2;
  u16* Cb  = (u16*)p;             p += NE * 2;
  u16* Wqt = (u16*)p;             p += (size_t)1024 * 1024 * 2;
  u16* Wkt = (u16*)p;             p += (size_t)1024 * 1024 * 2;
  u16* Wvt = (u16*)p;             p += (size_t)1024 * 1024 * 2;
  u16* Wot = (u16*)p;             p += (size_t)1024 * 1024 * 2;
  u16* Qb  = (u16*)p;             p += NE * 2;
  u16* Kb  = (u16*)p;             p += NE * 2;
  u16* Vtb = (u16*)p;             p += NE * 2;
  u16* Ab  = Xb;                  // alias: x-cast consumed before attention writes

  prep_kernel<<<5120, 256, 0, stream>>>(x, ctx, Wq, Wk, Wv, Wo,
                                        Xb, Cb, Wqt, Wkt, Wvt, Wot);
  proj_gemm_kernel<<<dim3(64, 8, 3), 256, 0, stream>>>(Xb, Cb, Wqt, Wkt, Wvt,
                                                       bq, bk, bv, Qb, Kb, Vtb);
  attn_kernel<<<1024, 256, 0, stream>>>(Qb, Kb, Vtb, Ab);
  out_gemm_kernel<<<dim3(64, 8), 256, 0, stream>>>(Ab, Wot, bo, out);
}

// Round 6
// 272.379 us; speedup vs baseline: 1.2495x; 1.2495x over previous
//
#include <hip/hip_runtime.h>
#include <stdint.h>

// ---------------- common types / helpers ----------------
using bf16x8 = __attribute__((ext_vector_type(8))) short;   // 8 bf16 (4 VGPRs)
using f32x4  = __attribute__((ext_vector_type(4))) float;
using f32x2  = __attribute__((ext_vector_type(2))) float;
using u16    = unsigned short;
using u16x4  = __attribute__((ext_vector_type(4))) unsigned short;
using u16x8  = __attribute__((ext_vector_type(8))) unsigned short;
using bf16x2v = __attribute__((ext_vector_type(2))) __bf16;

#define LOG2E 1.4426950408889634f

static __device__ __forceinline__ u16 bf16r(float f) {
  union { __bf16 h; u16 u; } v; v.h = (__bf16)f; return v.u;
}
static __device__ __forceinline__ unsigned pk2(float a, float b) {
  union { bf16x2v h; unsigned u; } r;
  r.h = __builtin_convertvector((f32x2){a, b}, bf16x2v);
  return r.u;
}
static __device__ __forceinline__ u16x4 pk4(float a, float b, float c, float d) {
  union { unsigned u[2]; u16x4 v; } r;
  r.u[0] = pk2(a, b); r.u[1] = pk2(c, d);
  return r.v;
}

static __device__ __forceinline__ void async_ld16(u16* lds, const u16* g) {
  __builtin_amdgcn_global_load_lds(
      (const __attribute__((address_space(1))) void*)g,
      (__attribute__((address_space(3))) void*)lds,
      16, 0, 0);
}

static __device__ __forceinline__ f32x4 mfma16(bf16x8 a, bf16x8 b, f32x4 c) {
  return __builtin_amdgcn_mfma_f32_16x16x32_bf16(a, b, c, 0, 0, 0);
}

// ---------------- kernel 1: fused prep (casts + weight transposes) ----------------
__global__ void prep_kernel(const float* __restrict__ x, const float* __restrict__ ctx,
                            const float* __restrict__ W0, const float* __restrict__ W1,
                            const float* __restrict__ W2, const float* __restrict__ W3,
                            u16* __restrict__ Xb, u16* __restrict__ Cb,
                            u16* __restrict__ T0, u16* __restrict__ T1,
                            u16* __restrict__ T2, u16* __restrict__ T3) {
  int bid = blockIdx.x;
  int t = threadIdx.x;
  if (bid < 4096) {
    const int n4 = 2097152;                       // float4s per tensor
    int i = bid * 256 + t;
    const int stride = 4096 * 256;
#pragma unroll
    for (int it = 0; it < 4; ++it, i += stride) {
      const float4* src = (i < n4) ? ((const float4*)x + i) : ((const float4*)ctx + (i - n4));
      u16x4* dst = (i < n4) ? ((u16x4*)Xb + i) : ((u16x4*)Cb + (i - n4));
      float4 v = *src;
      *dst = pk4(v.x, v.y, v.z, v.w);
    }
    return;
  }
  int b2 = bid - 4096;
  int z = b2 >> 8, rem = b2 & 255;
  const float* W = (z == 0) ? W0 : (z == 1) ? W1 : (z == 2) ? W2 : W3;
  u16* T = (z == 0) ? T0 : (z == 1) ? T1 : (z == 2) ? T2 : T3;
  __shared__ float tile[64][65];
  int k0 = (rem & 15) * 64, n0 = (rem >> 4) * 64;
#pragma unroll
  for (int i = 0; i < 4; ++i) {
    int kl = i * 16 + (t >> 4); int nl = (t & 15) * 4;
    float4 v = *(const float4*)(W + (size_t)(k0 + kl) * 1024 + n0 + nl);
    tile[kl][nl] = v.x; tile[kl][nl + 1] = v.y; tile[kl][nl + 2] = v.z; tile[kl][nl + 3] = v.w;
  }
  __syncthreads();
#pragma unroll
  for (int i = 0; i < 16; ++i) {
    int idx = i * 256 + t; int nl = idx >> 6; int kl = idx & 63;
    T[(size_t)(n0 + nl) * 1024 + k0 + kl] = bf16r(tile[kl][nl]);
  }
}

// ---------------- kernel 2: QKV projection GEMM (128x128 tile, dbuf LDS, counted vmcnt) ----------------
__global__ __launch_bounds__(256, 2) void proj_gemm_kernel(
    const u16* __restrict__ Xb, const u16* __restrict__ Cb,
    const u16* __restrict__ Wqt, const u16* __restrict__ Wkt, const u16* __restrict__ Wvt,
    const float* __restrict__ bq, const float* __restrict__ bk, const float* __restrict__ bv,
    u16* __restrict__ Qo, u16* __restrict__ Ko, u16* __restrict__ Vo) {
  __shared__ u16 smem[32768];           // A dbuf 2x[128][64] @0, B dbuf 2x[128][64] @16384  (64 KB)
  u16* sA = smem;
  u16* sB = smem + 16384;
  int z = blockIdx.z;
  const u16* A    = (z == 0) ? Xb : Cb;
  const u16* Bt   = (z == 0) ? Wqt : (z == 1) ? Wkt : Wvt;
  const float* bias = (z == 0) ? bq : (z == 1) ? bk : bv;
  int m0 = blockIdx.x * 128, n0 = blockIdx.y * 128;
  int t = threadIdx.x, w = t >> 6, lane = t & 63, quad = lane >> 4, lc = lane & 15;
  int wm = (w & 1) * 64, wn = (w >> 1) * 64;
  int sx = lc & 7;

  f32x4 acc[4][4];
  f32x4 z4 = {0.f, 0.f, 0.f, 0.f};
#pragma unroll
  for (int i = 0; i < 4; ++i)
#pragma unroll
    for (int j = 0; j < 4; ++j) acc[i][j] = z4;

  const u16* Abase = A  + (size_t)m0 * 1024;
  const u16* Bbase = Bt + (size_t)n0 * 1024;

  auto STAGE = [&](int s, int kt) {
#pragma unroll
    for (int i = 0; i < 4; ++i) {                 // A: 128 rows x 64 cols
      int c = i * 256 + t; int row = c >> 3; int cc = c & 7;
      async_ld16(sA + s * 8192 + c * 8,
                 Abase + (size_t)row * 1024 + kt * 64 + ((cc ^ (row & 7)) * 8));
    }
#pragma unroll
    for (int i = 0; i < 4; ++i) {                 // B: 128 rows x 64 cols
      int c = i * 256 + t; int row = c >> 3; int cc = c & 7;
      async_ld16(sB + s * 8192 + c * 8,
                 Bbase + (size_t)row * 1024 + kt * 64 + ((cc ^ (row & 7)) * 8));
    }
  };

  STAGE(0, 0);
  STAGE(1, 1);

  for (int kt = 0; kt < 16; ++kt) {
    int s = kt & 1;
    if (kt < 15) asm volatile("s_waitcnt vmcnt(8)" ::: "memory");   // tile kt landed; kt+1 in flight
    else         asm volatile("s_waitcnt vmcnt(0)" ::: "memory");
    __builtin_amdgcn_s_barrier();
    const u16* pA = sA + s * 8192;
    const u16* pB = sB + s * 8192;
#pragma unroll
    for (int ks = 0; ks < 2; ++ks) {
      bf16x8 af[4], bfr[4];
#pragma unroll
      for (int i = 0; i < 4; ++i)
        af[i]  = *(const bf16x8*)(pA + (wm + i * 16 + lc) * 64 + (((ks * 4 + quad) ^ sx)) * 8);
#pragma unroll
      for (int i = 0; i < 4; ++i)
        bfr[i] = *(const bf16x8*)(pB + (wn + i * 16 + lc) * 64 + (((ks * 4 + quad) ^ sx)) * 8);
      __builtin_amdgcn_s_setprio(1);
#pragma unroll
      for (int qi = 0; qi < 4; ++qi)
#pragma unroll
        for (int nj = 0; nj < 4; ++nj) acc[qi][nj] = mfma16(af[qi], bfr[nj], acc[qi][nj]);
      __builtin_amdgcn_s_setprio(0);
    }
    __builtin_amdgcn_s_barrier();                 // all waves done reading slot s
    if (kt < 14) STAGE(s, kt + 2);                // overwrite freed slot, 1 tile ahead
  }

  if (z < 2) {
    u16* dst = (z == 0) ? Qo : Ko;
    float scl = (z == 0) ? 0.125f * LOG2E : 1.0f;   // fold softmax scale + log2e into Q
#pragma unroll
    for (int qi = 0; qi < 4; ++qi)
#pragma unroll
      for (int nj = 0; nj < 4; ++nj) {
        int n = n0 + wn + nj * 16 + lc;
        float bvv = bias[n];
        int hh = n >> 6, d = n & 63;
#pragma unroll
        for (int r = 0; r < 4; ++r) {
          int m = m0 + wm + qi * 16 + quad * 4 + r;
          int bb = m >> 10, pos = m & 1023;
          float v = (acc[qi][nj][r] + bvv) * scl;
          dst[((size_t)(bb * 16 + hh) * 1024 + pos) * 64 + d] = bf16r(v);
        }
      }
  } else {
    // V: write transposed [B,H,64,NKV] via per-wave LDS transpose
    __syncthreads();                      // all waves done with staging LDS
    u16* Tw = smem + w * (64 * 66);
    int hh = (n0 + wn) >> 6;
    int mb = m0 + wm; int bb = mb >> 10; int pos0 = mb & 1023;
#pragma unroll
    for (int qi = 0; qi < 4; ++qi)
#pragma unroll
      for (int nj = 0; nj < 4; ++nj) {
        int lcc = nj * 16 + lc;
        float bvv = bias[n0 + wn + lcc];
#pragma unroll
        for (int r = 0; r < 4; ++r) {
          int lr = qi * 16 + quad * 4 + r;
          Tw[lr * 66 + lcc] = bf16r(acc[qi][nj][r] + bvv);
        }
      }
#pragma unroll
    for (int i = 0; i < 8; ++i) {
      int dl = i * 8 + (lane >> 3); int kv0 = (lane & 7) * 8;
      u16x8 pk;
#pragma unroll
      for (int j = 0; j < 8; ++j) pk[j] = Tw[(kv0 + j) * 66 + dl];
      *(u16x8*)(Vo + ((size_t)(bb * 16 + hh) * 64 + dl) * 1024 + pos0 + kv0) = pk;
    }
  }
}

// ---------------- kernel 3: flash attention (kv-tile=64, single-buffer + split staging, 4 blocks/CU) ----------------
__global__ __launch_bounds__(256, 4) void attn_kernel(const u16* __restrict__ Qb,
                                                      const u16* __restrict__ Kb,
                                                      const u16* __restrict__ Vt,
                                                      u16* __restrict__ Ab) {
  // layout (u16 units): K@0 (4096), V@4096 (4096), P@8192 (8192)  = 32 KB
  __shared__ u16 smem[16384];
  u16* sK = smem;
  u16* sV = smem + 4096;
  u16* sP = smem + 8192;          // 8192 u16 [128q][64kv] swizzled
  int bid = blockIdx.x;
  int bh = (bid & 7) | ((bid >> 6) << 3);   // XCD-local K/V reuse
  int qt = (bid >> 3) & 7;
  int bb = bh >> 4, hh = bh & 15;
  int t = threadIdx.x, w = t >> 6, lane = t & 63, quad = lane >> 4, lc = lane & 15;

  const u16* Qg = Qb + ((size_t)bh * 1024 + qt * 128 + w * 32) * 64;
  bf16x8 qf[2][2];
#pragma unroll
  for (int qi = 0; qi < 2; ++qi)
#pragma unroll
    for (int ks = 0; ks < 2; ++ks)
      qf[qi][ks] = *(const bf16x8*)(Qg + (qi * 16 + lc) * 64 + ks * 32 + quad * 8);

  f32x4 O[4][2];
  f32x4 z4 = {0.f, 0.f, 0.f, 0.f};
#pragma unroll
  for (int dj = 0; dj < 4; ++dj) { O[dj][0] = z4; O[dj][1] = z4; }
  float l_lane[2] = {0.f, 0.f};

  const u16* Kg = Kb + (size_t)bh * 65536;
  const u16* Vg = Vt + (size_t)bh * 65536;
  int r0 = t >> 3, gs = t & 7;

  auto STAGE_K = [&](int kt) {
#pragma unroll
    for (int i = 0; i < 2; ++i) {
      int r = r0 + i * 32;
      async_ld16(sK + i * 2048 + t * 8, Kg + (size_t)(kt * 64 + r) * 64 + (gs ^ (r & 7)) * 8);
    }
  };
  auto STAGE_V = [&](int kt) {
#pragma unroll
    for (int i = 0; i < 2; ++i) {
      int d = r0 + i * 32;
      async_ld16(sV + i * 2048 + t * 8, Vg + (size_t)d * 1024 + kt * 64 + (gs ^ (d & 7)) * 8);
    }
  };

  STAGE_K(0);                                    // 2 loads in flight (oldest)
  STAGE_V(0);                                    // +2

  for (int kt = 0; kt < 16; ++kt) {
    // wait own K loads (FIFO: K issued before V); V may still be in flight
    asm volatile("s_waitcnt vmcnt(2)" ::: "memory");
    __builtin_amdgcn_s_barrier();                // all waves' K[kt] landed

    f32x4 s[4][2];
#pragma unroll
    for (int kj = 0; kj < 4; ++kj) { s[kj][0] = z4; s[kj][1] = z4; }
    __builtin_amdgcn_s_setprio(1);
#pragma unroll
    for (int kj = 0; kj < 4; ++kj) {
      int kv = kj * 16 + lc;
#pragma unroll
      for (int ks = 0; ks < 2; ++ks) {
        bf16x8 a = *(const bf16x8*)(sK + kv * 64 + ((ks * 4 + quad) ^ (kv & 7)) * 8);
        s[kj][0] = mfma16(a, qf[0][ks], s[kj][0]);
        s[kj][1] = mfma16(a, qf[1][ks], s[kj][1]);
      }
    }
    __builtin_amdgcn_s_setprio(0);

#pragma unroll
    for (int qi = 0; qi < 2; ++qi) {
      int q = w * 32 + qi * 16 + lc;
#pragma unroll
      for (int kj = 0; kj < 4; ++kj) {
        float p0 = exp2f(s[kj][qi][0]);
        float p1 = exp2f(s[kj][qi][1]);
        float p2 = exp2f(s[kj][qi][2]);
        float p3 = exp2f(s[kj][qi][3]);
        l_lane[qi] += (p0 + p1) + (p2 + p3);
        int g = kj * 2 + (quad >> 1);
        *(u16x4*)(sP + q * 64 + ((g ^ (q & 7)) * 8) + (quad & 1) * 4) = pk4(p0, p1, p2, p3);
      }
    }

    // wait own V loads; barrier => all waves' V landed AND all waves done with K reads
    asm volatile("s_waitcnt vmcnt(0)" ::: "memory");
    __builtin_amdgcn_s_barrier();
    if (kt < 15) STAGE_K(kt + 1);                // K slot free now; consumed next iter

    __builtin_amdgcn_s_setprio(1);
#pragma unroll
    for (int ks = 0; ks < 2; ++ks) {
      bf16x8 pb[2];
#pragma unroll
      for (int qi = 0; qi < 2; ++qi) {
        int q = w * 32 + qi * 16 + lc;
        pb[qi] = *(const bf16x8*)(sP + q * 64 + (((ks * 4 + quad) ^ (q & 7))) * 8);
      }
#pragma unroll
      for (int dj = 0; dj < 4; ++dj) {
        int d = dj * 16 + lc;
        bf16x8 va = *(const bf16x8*)(sV + d * 64 + (((ks * 4 + quad) ^ (d & 7))) * 8);
        O[dj][0] = mfma16(va, pb[0], O[dj][0]);
        O[dj][1] = mfma16(va, pb[1], O[dj][1]);
      }
    }
    __builtin_amdgcn_s_setprio(0);

    __builtin_amdgcn_s_barrier();                // all waves done with V reads
    if (kt < 15) STAGE_V(kt + 1);                // V slot free; consumed after next QK+softmax
  }

  float inv[2];
#pragma unroll
  for (int qi = 0; qi < 2; ++qi) {
    float l = l_lane[qi];
    l += __shfl_xor(l, 16);
    l += __shfl_xor(l, 32);
    inv[qi] = 1.f / l;
  }

  __syncthreads();
  u16* myP = smem + w * 2304;
#pragma unroll
  for (int qi = 0; qi < 2; ++qi)
#pragma unroll
    for (int dj = 0; dj < 4; ++dj)
      *(u16x4*)(myP + (qi * 16 + lc) * 72 + dj * 16 + quad * 4) =
          pk4(O[dj][qi][0] * inv[qi], O[dj][qi][1] * inv[qi],
              O[dj][qi][2] * inv[qi], O[dj][qi][3] * inv[qi]);
#pragma unroll
  for (int i = 0; i < 4; ++i) {
    int idx = i * 64 + lane; int ql = idx >> 3; int dg = idx & 7;
    u16x8 pk = *(const u16x8*)(myP + ql * 72 + dg * 8);
    *(u16x8*)(Ab + ((size_t)bb * 1024 + qt * 128 + w * 32 + ql) * 1024 + hh * 64 + dg * 8) = pk;
  }
}

// ---------------- kernel 4: output projection GEMM (128x128 tile, dbuf, counted vmcnt), fp32 out ----------------
__global__ __launch_bounds__(256, 2) void out_gemm_kernel(const u16* __restrict__ A,
                                                          const u16* __restrict__ Bt,
                                                          const float* __restrict__ bo,
                                                          float* __restrict__ out) {
  __shared__ u16 smem[32768];
  u16* sA = smem;
  u16* sB = smem + 16384;
  int m0 = blockIdx.x * 128, n0 = blockIdx.y * 128;
  int t = threadIdx.x, w = t >> 6, lane = t & 63, quad = lane >> 4, lc = lane & 15;
  int wm = (w & 1) * 64, wn = (w >> 1) * 64;
  int sx = lc & 7;
  f32x4 acc[4][4];
  f32x4 z4 = {0.f, 0.f, 0.f, 0.f};
#pragma unroll
  for (int i = 0; i < 4; ++i)
#pragma unroll
    for (int j = 0; j < 4; ++j) acc[i][j] = z4;

  const u16* Abase = A  + (size_t)m0 * 1024;
  const u16* Bbase = Bt + (size_t)n0 * 1024;

  auto STAGE = [&](int s, int kt) {
#pragma unroll
    for (int i = 0; i < 4; ++i) {
      int c = i * 256 + t; int row = c >> 3; int cc = c & 7;
      async_ld16(sA + s * 8192 + c * 8,
                 Abase + (size_t)row * 1024 + kt * 64 + ((cc ^ (row & 7)) * 8));
    }
#pragma unroll
    for (int i = 0; i < 4; ++i) {
      int c = i * 256 + t; int row = c >> 3; int cc = c & 7;
      async_ld16(sB + s * 8192 + c * 8,
                 Bbase + (size_t)row * 1024 + kt * 64 + ((cc ^ (row & 7)) * 8));
    }
  };

  STAGE(0, 0);
  STAGE(1, 1);

  for (int kt = 0; kt < 16; ++kt) {
    int s = kt & 1;
    if (kt < 15) asm volatile("s_waitcnt vmcnt(8)" ::: "memory");
    else         asm volatile("s_waitcnt vmcnt(0)" ::: "memory");
    __builtin_amdgcn_s_barrier();
    const u16* pA = sA + s * 8192;
    const u16* pB = sB + s * 8192;
#pragma unroll
    for (int ks = 0; ks < 2; ++ks) {
      bf16x8 af[4], bfr[4];
#pragma unroll
      for (int i = 0; i < 4; ++i)
        af[i]  = *(const bf16x8*)(pA + (wm + i * 16 + lc) * 64 + (((ks * 4 + quad) ^ sx)) * 8);
#pragma unroll
      for (int i = 0; i < 4; ++i)
        bfr[i] = *(const bf16x8*)(pB + (wn + i * 16 + lc) * 64 + (((ks * 4 + quad) ^ sx)) * 8);
      __builtin_amdgcn_s_setprio(1);
#pragma unroll
      for (int qi = 0; qi < 4; ++qi)
#pragma unroll
        for (int nj = 0; nj < 4; ++nj) acc[qi][nj] = mfma16(af[qi], bfr[nj], acc[qi][nj]);
      __builtin_amdgcn_s_setprio(0);
    }
    __builtin_amdgcn_s_barrier();
    if (kt < 14) STAGE(s, kt + 2);
  }

#pragma unroll
  for (int qi = 0; qi < 4; ++qi)
#pragma unroll
    for (int nj = 0; nj < 4; ++nj) {
      int n = n0 + wn + nj * 16 + lc;
      float bvv = bo[n];
#pragma unroll
      for (int r = 0; r < 4; ++r) {
        int m = m0 + wm + qi * 16 + quad * 4 + r;
        out[(size_t)m * 1024 + n] = acc[qi][nj][r] + bvv;
      }
    }
}

// ---------------- host ----------------
extern "C" void kernel_launch(void* const* d_in, const int* in_sizes, int n_in,
                              void* d_out, int out_size, void* d_ws, size_t ws_size,
                              hipStream_t stream) {
  const float* x   = (const float*)d_in[0];
  const float* ctx = (const float*)d_in[1];
  const float* Wq  = (const float*)d_in[2];
  const float* bq  = (const float*)d_in[3];
  const float* Wk  = (const float*)d_in[4];
  const float* bk  = (const float*)d_in[5];
  const float* Wv  = (const float*)d_in[6];
  const float* bv  = (const float*)d_in[7];
  const float* Wo  = (const float*)d_in[8];
  const float* bo  = (const float*)d_in[9];
  float* out = (float*)d_out;

  const size_t NE = (size_t)8192 * 1024;
  char* p = (char*)d_ws;
  u16* Xb  = (u16*)p;             p += NE * 2;
  u16* Cb  = (u16*)p;             p += NE * 2;
  u16* Wqt = (u16*)p;             p += (size_t)1024 * 1024 * 2;
  u16* Wkt = (u16*)p;             p += (size_t)1024 * 1024 * 2;
  u16* Wvt = (u16*)p;             p += (size_t)1024 * 1024 * 2;
  u16* Wot = (u16*)p;             p += (size_t)1024 * 1024 * 2;
  u16* Qb  = (u16*)p;             p += NE * 2;
  u16* Kb  = (u16*)p;             p += NE * 2;
  u16* Vtb = (u16*)p;             p += NE * 2;
  u16* Ab  = Xb;                  // alias: x-cast consumed before attention writes

  prep_kernel<<<5120, 256, 0, stream>>>(x, ctx, Wq, Wk, Wv, Wo,
                                        Xb, Cb, Wqt, Wkt, Wvt, Wot);
  proj_gemm_kernel<<<dim3(64, 8, 3), 256, 0, stream>>>(Xb, Cb, Wqt, Wkt, Wvt,
                                                       bq, bk, bv, Qb, Kb, Vtb);
  attn_kernel<<<1024, 256, 0, stream>>>(Qb, Kb, Vtb, Ab);
  out_gemm_kernel<<<dim3(64, 8), 256, 0, stream>>>(Ab, Wot, bo, out);
}

// Round 7
// 251.206 us; speedup vs baseline: 1.3548x; 1.0843x over previous
//
#include <hip/hip_runtime.h>
#include <stdint.h>

// ---------------- common types / helpers ----------------
using bf16x8 = __attribute__((ext_vector_type(8))) short;   // 8 bf16 (4 VGPRs)
using f32x4  = __attribute__((ext_vector_type(4))) float;
using f32x2  = __attribute__((ext_vector_type(2))) float;
using u16    = unsigned short;
using u16x4  = __attribute__((ext_vector_type(4))) unsigned short;
using u16x8  = __attribute__((ext_vector_type(8))) unsigned short;
using bf16x2v = __attribute__((ext_vector_type(2))) __bf16;

#define LOG2E 1.4426950408889634f

#if __has_builtin(__builtin_amdgcn_exp2f)
#define fast_exp2(x) __builtin_amdgcn_exp2f(x)   // raw v_exp_f32, no OCML guard code
#else
#define fast_exp2(x) exp2f(x)
#endif

static __device__ __forceinline__ u16 bf16r(float f) {
  union { __bf16 h; u16 u; } v; v.h = (__bf16)f; return v.u;
}
static __device__ __forceinline__ unsigned pk2(float a, float b) {
  union { bf16x2v h; unsigned u; } r;
  r.h = __builtin_convertvector((f32x2){a, b}, bf16x2v);
  return r.u;
}
static __device__ __forceinline__ u16x4 pk4(float a, float b, float c, float d) {
  union { unsigned u[2]; u16x4 v; } r;
  r.u[0] = pk2(a, b); r.u[1] = pk2(c, d);
  return r.v;
}

static __device__ __forceinline__ void async_ld16(u16* lds, const u16* g) {
  __builtin_amdgcn_global_load_lds(
      (const __attribute__((address_space(1))) void*)g,
      (__attribute__((address_space(3))) void*)lds,
      16, 0, 0);
}

static __device__ __forceinline__ f32x4 mfma16(bf16x8 a, bf16x8 b, f32x4 c) {
  return __builtin_amdgcn_mfma_f32_16x16x32_bf16(a, b, c, 0, 0, 0);
}

// ---------------- kernel 1: fused prep (casts + weight transposes) ----------------
__global__ void prep_kernel(const float* __restrict__ x, const float* __restrict__ ctx,
                            const float* __restrict__ W0, const float* __restrict__ W1,
                            const float* __restrict__ W2, const float* __restrict__ W3,
                            u16* __restrict__ Xb, u16* __restrict__ Cb,
                            u16* __restrict__ T0, u16* __restrict__ T1,
                            u16* __restrict__ T2, u16* __restrict__ T3) {
  int bid = blockIdx.x;
  int t = threadIdx.x;
  if (bid < 4096) {
    const int n4 = 2097152;                       // float4s per tensor
    int i = bid * 256 + t;
    const int stride = 4096 * 256;
#pragma unroll
    for (int it = 0; it < 4; ++it, i += stride) {
      const float4* src = (i < n4) ? ((const float4*)x + i) : ((const float4*)ctx + (i - n4));
      u16x4* dst = (i < n4) ? ((u16x4*)Xb + i) : ((u16x4*)Cb + (i - n4));
      float4 v = *src;
      *dst = pk4(v.x, v.y, v.z, v.w);
    }
    return;
  }
  int b2 = bid - 4096;
  int z = b2 >> 8, rem = b2 & 255;
  const float* W = (z == 0) ? W0 : (z == 1) ? W1 : (z == 2) ? W2 : W3;
  u16* T = (z == 0) ? T0 : (z == 1) ? T1 : (z == 2) ? T2 : T3;
  __shared__ float tile[64][65];
  int k0 = (rem & 15) * 64, n0 = (rem >> 4) * 64;
#pragma unroll
  for (int i = 0; i < 4; ++i) {
    int kl = i * 16 + (t >> 4); int nl = (t & 15) * 4;
    float4 v = *(const float4*)(W + (size_t)(k0 + kl) * 1024 + n0 + nl);
    tile[kl][nl] = v.x; tile[kl][nl + 1] = v.y; tile[kl][nl + 2] = v.z; tile[kl][nl + 3] = v.w;
  }
  __syncthreads();
#pragma unroll
  for (int i = 0; i < 16; ++i) {
    int idx = i * 256 + t; int nl = idx >> 6; int kl = idx & 63;
    T[(size_t)(n0 + nl) * 1024 + k0 + kl] = bf16r(tile[kl][nl]);
  }
}

// ---------------- kernel 2: QKV projection GEMM (128x128 tile, dbuf LDS, counted vmcnt) ----------------
__global__ __launch_bounds__(256, 2) void proj_gemm_kernel(
    const u16* __restrict__ Xb, const u16* __restrict__ Cb,
    const u16* __restrict__ Wqt, const u16* __restrict__ Wkt, const u16* __restrict__ Wvt,
    const float* __restrict__ bq, const float* __restrict__ bk, const float* __restrict__ bv,
    u16* __restrict__ Qo, u16* __restrict__ Ko, u16* __restrict__ Vo) {
  __shared__ u16 smem[32768];           // A dbuf 2x[128][64] @0, B dbuf 2x[128][64] @16384  (64 KB)
  u16* sA = smem;
  u16* sB = smem + 16384;
  int z = blockIdx.z;
  const u16* A    = (z == 0) ? Xb : Cb;
  const u16* Bt   = (z == 0) ? Wqt : (z == 1) ? Wkt : Wvt;
  const float* bias = (z == 0) ? bq : (z == 1) ? bk : bv;
  int m0 = blockIdx.x * 128, n0 = blockIdx.y * 128;
  int t = threadIdx.x, w = t >> 6, lane = t & 63, quad = lane >> 4, lc = lane & 15;
  int wm = (w & 1) * 64, wn = (w >> 1) * 64;
  int sx = lc & 7;

  f32x4 acc[4][4];
  f32x4 z4 = {0.f, 0.f, 0.f, 0.f};
#pragma unroll
  for (int i = 0; i < 4; ++i)
#pragma unroll
    for (int j = 0; j < 4; ++j) acc[i][j] = z4;

  const u16* Abase = A  + (size_t)m0 * 1024;
  const u16* Bbase = Bt + (size_t)n0 * 1024;

  auto STAGE = [&](int s, int kt) {
#pragma unroll
    for (int i = 0; i < 4; ++i) {                 // A: 128 rows x 64 cols
      int c = i * 256 + t; int row = c >> 3; int cc = c & 7;
      async_ld16(sA + s * 8192 + c * 8,
                 Abase + (size_t)row * 1024 + kt * 64 + ((cc ^ (row & 7)) * 8));
    }
#pragma unroll
    for (int i = 0; i < 4; ++i) {                 // B: 128 rows x 64 cols
      int c = i * 256 + t; int row = c >> 3; int cc = c & 7;
      async_ld16(sB + s * 8192 + c * 8,
                 Bbase + (size_t)row * 1024 + kt * 64 + ((cc ^ (row & 7)) * 8));
    }
  };

  STAGE(0, 0);
  STAGE(1, 1);

  for (int kt = 0; kt < 16; ++kt) {
    int s = kt & 1;
    if (kt < 15) asm volatile("s_waitcnt vmcnt(8)" ::: "memory");   // tile kt landed; kt+1 in flight
    else         asm volatile("s_waitcnt vmcnt(0)" ::: "memory");
    __builtin_amdgcn_s_barrier();
    const u16* pA = sA + s * 8192;
    const u16* pB = sB + s * 8192;
#pragma unroll
    for (int ks = 0; ks < 2; ++ks) {
      bf16x8 af[4], bfr[4];
#pragma unroll
      for (int i = 0; i < 4; ++i)
        af[i]  = *(const bf16x8*)(pA + (wm + i * 16 + lc) * 64 + (((ks * 4 + quad) ^ sx)) * 8);
#pragma unroll
      for (int i = 0; i < 4; ++i)
        bfr[i] = *(const bf16x8*)(pB + (wn + i * 16 + lc) * 64 + (((ks * 4 + quad) ^ sx)) * 8);
      __builtin_amdgcn_s_setprio(1);
#pragma unroll
      for (int qi = 0; qi < 4; ++qi)
#pragma unroll
        for (int nj = 0; nj < 4; ++nj) acc[qi][nj] = mfma16(af[qi], bfr[nj], acc[qi][nj]);
      __builtin_amdgcn_s_setprio(0);
    }
    __builtin_amdgcn_s_barrier();                 // all waves done reading slot s
    if (kt < 14) STAGE(s, kt + 2);                // overwrite freed slot, 1 tile ahead
  }

  if (z < 2) {
    u16* dst = (z == 0) ? Qo : Ko;
    float scl = (z == 0) ? 0.125f * LOG2E : 1.0f;   // fold softmax scale + log2e into Q
#pragma unroll
    for (int qi = 0; qi < 4; ++qi)
#pragma unroll
      for (int nj = 0; nj < 4; ++nj) {
        int n = n0 + wn + nj * 16 + lc;
        float bvv = bias[n];
        int hh = n >> 6, d = n & 63;
#pragma unroll
        for (int r = 0; r < 4; ++r) {
          int m = m0 + wm + qi * 16 + quad * 4 + r;
          int bb = m >> 10, pos = m & 1023;
          float v = (acc[qi][nj][r] + bvv) * scl;
          dst[((size_t)(bb * 16 + hh) * 1024 + pos) * 64 + d] = bf16r(v);
        }
      }
  } else {
    // V: write transposed [B,H,64,NKV] via per-wave LDS transpose
    __syncthreads();                      // all waves done with staging LDS
    u16* Tw = smem + w * (64 * 66);
    int hh = (n0 + wn) >> 6;
    int mb = m0 + wm; int bb = mb >> 10; int pos0 = mb & 1023;
#pragma unroll
    for (int qi = 0; qi < 4; ++qi)
#pragma unroll
      for (int nj = 0; nj < 4; ++nj) {
        int lcc = nj * 16 + lc;
        float bvv = bias[n0 + wn + lcc];
#pragma unroll
        for (int r = 0; r < 4; ++r) {
          int lr = qi * 16 + quad * 4 + r;
          Tw[lr * 66 + lcc] = bf16r(acc[qi][nj][r] + bvv);
        }
      }
#pragma unroll
    for (int i = 0; i < 8; ++i) {
      int dl = i * 8 + (lane >> 3); int kv0 = (lane & 7) * 8;
      u16x8 pk;
#pragma unroll
      for (int j = 0; j < 8; ++j) pk[j] = Tw[(kv0 + j) * 66 + dl];
      *(u16x8*)(Vo + ((size_t)(bb * 16 + hh) * 64 + dl) * 1024 + pos0 + kv0) = pk;
    }
  }
}

// ---------------- kernel 3: flash attention (kv-tile=64, single-buffer + split staging, 4 blocks/CU) ----------------
__global__ __launch_bounds__(256, 4) void attn_kernel(const u16* __restrict__ Qb,
                                                      const u16* __restrict__ Kb,
                                                      const u16* __restrict__ Vt,
                                                      u16* __restrict__ Ab) {
  // layout (u16 units): K@0 (4096), V@4096 (4096), P@8192 (8192)  = 32 KB
  __shared__ u16 smem[16384];
  u16* sK = smem;
  u16* sV = smem + 4096;
  u16* sP = smem + 8192;          // 8192 u16 [128q][64kv] swizzled
  int bid = blockIdx.x;
  int bh = (bid & 7) | ((bid >> 6) << 3);   // XCD-local K/V reuse
  int qt = (bid >> 3) & 7;
  int bb = bh >> 4, hh = bh & 15;
  int t = threadIdx.x, w = t >> 6, lane = t & 63, quad = lane >> 4, lc = lane & 15;

  const u16* Qg = Qb + ((size_t)bh * 1024 + qt * 128 + w * 32) * 64;
  bf16x8 qf[2][2];
#pragma unroll
  for (int qi = 0; qi < 2; ++qi)
#pragma unroll
    for (int ks = 0; ks < 2; ++ks)
      qf[qi][ks] = *(const bf16x8*)(Qg + (qi * 16 + lc) * 64 + ks * 32 + quad * 8);

  f32x4 O[4][2];
  f32x4 z4 = {0.f, 0.f, 0.f, 0.f};
#pragma unroll
  for (int dj = 0; dj < 4; ++dj) { O[dj][0] = z4; O[dj][1] = z4; }
  float l_lane[2] = {0.f, 0.f};

  const u16* Kg = Kb + (size_t)bh * 65536;
  const u16* Vg = Vt + (size_t)bh * 65536;
  int r0 = t >> 3, gs = t & 7;

  auto STAGE_K = [&](int kt) {
#pragma unroll
    for (int i = 0; i < 2; ++i) {
      int r = r0 + i * 32;
      async_ld16(sK + i * 2048 + t * 8, Kg + (size_t)(kt * 64 + r) * 64 + (gs ^ (r & 7)) * 8);
    }
  };
  auto STAGE_V = [&](int kt) {
#pragma unroll
    for (int i = 0; i < 2; ++i) {
      int d = r0 + i * 32;
      async_ld16(sV + i * 2048 + t * 8, Vg + (size_t)d * 1024 + kt * 64 + (gs ^ (d & 7)) * 8);
    }
  };

  STAGE_K(0);                                    // 2 loads in flight (oldest)
  STAGE_V(0);                                    // +2

  for (int kt = 0; kt < 16; ++kt) {
    // wait own K loads (FIFO: K issued before V); V may still be in flight
    asm volatile("s_waitcnt vmcnt(2)" ::: "memory");
    __builtin_amdgcn_s_barrier();                // all waves' K[kt] landed

    f32x4 s[4][2];
#pragma unroll
    for (int kj = 0; kj < 4; ++kj) { s[kj][0] = z4; s[kj][1] = z4; }
    __builtin_amdgcn_s_setprio(1);
#pragma unroll
    for (int kj = 0; kj < 4; ++kj) {
      int kv = kj * 16 + lc;
#pragma unroll
      for (int ks = 0; ks < 2; ++ks) {
        bf16x8 a = *(const bf16x8*)(sK + kv * 64 + ((ks * 4 + quad) ^ (kv & 7)) * 8);
        s[kj][0] = mfma16(a, qf[0][ks], s[kj][0]);
        s[kj][1] = mfma16(a, qf[1][ks], s[kj][1]);
      }
    }
    __builtin_amdgcn_s_setprio(0);

#pragma unroll
    for (int qi = 0; qi < 2; ++qi) {
      int q = w * 32 + qi * 16 + lc;
#pragma unroll
      for (int kj = 0; kj < 4; ++kj) {
        float p0 = fast_exp2(s[kj][qi][0]);
        float p1 = fast_exp2(s[kj][qi][1]);
        float p2 = fast_exp2(s[kj][qi][2]);
        float p3 = fast_exp2(s[kj][qi][3]);
        l_lane[qi] += (p0 + p1) + (p2 + p3);
        int g = kj * 2 + (quad >> 1);
        *(u16x4*)(sP + q * 64 + ((g ^ (q & 7)) * 8) + (quad & 1) * 4) = pk4(p0, p1, p2, p3);
      }
    }

    // wait own V loads; barrier => all waves' V landed AND all waves done with K reads
    asm volatile("s_waitcnt vmcnt(0)" ::: "memory");
    __builtin_amdgcn_s_barrier();
    if (kt < 15) STAGE_K(kt + 1);                // K slot free now; consumed next iter

    __builtin_amdgcn_s_setprio(1);
#pragma unroll
    for (int ks = 0; ks < 2; ++ks) {
      bf16x8 pb[2];
#pragma unroll
      for (int qi = 0; qi < 2; ++qi) {
        int q = w * 32 + qi * 16 + lc;
        pb[qi] = *(const bf16x8*)(sP + q * 64 + (((ks * 4 + quad) ^ (q & 7))) * 8);
      }
#pragma unroll
      for (int dj = 0; dj < 4; ++dj) {
        int d = dj * 16 + lc;
        bf16x8 va = *(const bf16x8*)(sV + d * 64 + (((ks * 4 + quad) ^ (d & 7))) * 8);
        O[dj][0] = mfma16(va, pb[0], O[dj][0]);
        O[dj][1] = mfma16(va, pb[1], O[dj][1]);
      }
    }
    __builtin_amdgcn_s_setprio(0);

    __builtin_amdgcn_s_barrier();                // all waves done with V reads
    if (kt < 15) STAGE_V(kt + 1);                // V slot free; consumed after next QK+softmax
  }

  float inv[2];
#pragma unroll
  for (int qi = 0; qi < 2; ++qi) {
    float l = l_lane[qi];
    l += __shfl_xor(l, 16);
    l += __shfl_xor(l, 32);
    inv[qi] = 1.f / l;
  }

  __syncthreads();
  u16* myP = smem + w * 2304;
#pragma unroll
  for (int qi = 0; qi < 2; ++qi)
#pragma unroll
    for (int dj = 0; dj < 4; ++dj)
      *(u16x4*)(myP + (qi * 16 + lc) * 72 + dj * 16 + quad * 4) =
          pk4(O[dj][qi][0] * inv[qi], O[dj][qi][1] * inv[qi],
              O[dj][qi][2] * inv[qi], O[dj][qi][3] * inv[qi]);
#pragma unroll
  for (int i = 0; i < 4; ++i) {
    int idx = i * 64 + lane; int ql = idx >> 3; int dg = idx & 7;
    u16x8 pk = *(const u16x8*)(myP + ql * 72 + dg * 8);
    *(u16x8*)(Ab + ((size_t)bb * 1024 + qt * 128 + w * 32 + ql) * 1024 + hh * 64 + dg * 8) = pk;
  }
}

// ---------------- kernel 4: output projection GEMM (128x128 tile, dbuf, counted vmcnt), fp32 out ----------------
__global__ __launch_bounds__(256, 2) void out_gemm_kernel(const u16* __restrict__ A,
                                                          const u16* __restrict__ Bt,
                                                          const float* __restrict__ bo,
                                                          float* __restrict__ out) {
  __shared__ u16 smem[32768];
  u16* sA = smem;
  u16* sB = smem + 16384;
  int m0 = blockIdx.x * 128, n0 = blockIdx.y * 128;
  int t = threadIdx.x, w = t >> 6, lane = t & 63, quad = lane >> 4, lc = lane & 15;
  int wm = (w & 1) * 64, wn = (w >> 1) * 64;
  int sx = lc & 7;
  f32x4 acc[4][4];
  f32x4 z4 = {0.f, 0.f, 0.f, 0.f};
#pragma unroll
  for (int i = 0; i < 4; ++i)
#pragma unroll
    for (int j = 0; j < 4; ++j) acc[i][j] = z4;

  const u16* Abase = A  + (size_t)m0 * 1024;
  const u16* Bbase = Bt + (size_t)n0 * 1024;

  auto STAGE = [&](int s, int kt) {
#pragma unroll
    for (int i = 0; i < 4; ++i) {
      int c = i * 256 + t; int row = c >> 3; int cc = c & 7;
      async_ld16(sA + s * 8192 + c * 8,
                 Abase + (size_t)row * 1024 + kt * 64 + ((cc ^ (row & 7)) * 8));
    }
#pragma unroll
    for (int i = 0; i < 4; ++i) {
      int c = i * 256 + t; int row = c >> 3; int cc = c & 7;
      async_ld16(sB + s * 8192 + c * 8,
                 Bbase + (size_t)row * 1024 + kt * 64 + ((cc ^ (row & 7)) * 8));
    }
  };

  STAGE(0, 0);
  STAGE(1, 1);

  for (int kt = 0; kt < 16; ++kt) {
    int s = kt & 1;
    if (kt < 15) asm volatile("s_waitcnt vmcnt(8)" ::: "memory");
    else         asm volatile("s_waitcnt vmcnt(0)" ::: "memory");
    __builtin_amdgcn_s_barrier();
    const u16* pA = sA + s * 8192;
    const u16* pB = sB + s * 8192;
#pragma unroll
    for (int ks = 0; ks < 2; ++ks) {
      bf16x8 af[4], bfr[4];
#pragma unroll
      for (int i = 0; i < 4; ++i)
        af[i]  = *(const bf16x8*)(pA + (wm + i * 16 + lc) * 64 + (((ks * 4 + quad) ^ sx)) * 8);
#pragma unroll
      for (int i = 0; i < 4; ++i)
        bfr[i] = *(const bf16x8*)(pB + (wn + i * 16 + lc) * 64 + (((ks * 4 + quad) ^ sx)) * 8);
      __builtin_amdgcn_s_setprio(1);
#pragma unroll
      for (int qi = 0; qi < 4; ++qi)
#pragma unroll
        for (int nj = 0; nj < 4; ++nj) acc[qi][nj] = mfma16(af[qi], bfr[nj], acc[qi][nj]);
      __builtin_amdgcn_s_setprio(0);
    }
    __builtin_amdgcn_s_barrier();
    if (kt < 14) STAGE(s, kt + 2);
  }

#pragma unroll
  for (int qi = 0; qi < 4; ++qi)
#pragma unroll
    for (int nj = 0; nj < 4; ++nj) {
      int n = n0 + wn + nj * 16 + lc;
      float bvv = bo[n];
#pragma unroll
      for (int r = 0; r < 4; ++r) {
        int m = m0 + wm + qi * 16 + quad * 4 + r;
        out[(size_t)m * 1024 + n] = acc[qi][nj][r] + bvv;
      }
    }
}

// ---------------- host ----------------
extern "C" void kernel_launch(void* const* d_in, const int* in_sizes, int n_in,
                              void* d_out, int out_size, void* d_ws, size_t ws_size,
                              hipStream_t stream) {
  const float* x   = (const float*)d_in[0];
  const float* ctx = (const float*)d_in[1];
  const float* Wq  = (const float*)d_in[2];
  const float* bq  = (const float*)d_in[3];
  const float* Wk  = (const float*)d_in[4];
  const float* bk  = (const float*)d_in[5];
  const float* Wv  = (const float*)d_in[6];
  const float* bv  = (const float*)d_in[7];
  const float* Wo  = (const float*)d_in[8];
  const float* bo  = (const float*)d_in[9];
  float* out = (float*)d_out;

  const size_t NE = (size_t)8192 * 1024;
  char* p = (char*)d_ws;
  u16* Xb  = (u16*)p;             p += NE * 2;
  u16* Cb  = (u16*)p;             p += NE * 2;
  u16* Wqt = (u16*)p;             p += (size_t)1024 * 1024 * 2;
  u16* Wkt = (u16*)p;             p += (size_t)1024 * 1024 * 2;
  u16* Wvt = (u16*)p;             p += (size_t)1024 * 1024 * 2;
  u16* Wot = (u16*)p;             p += (size_t)1024 * 1024 * 2;
  u16* Qb  = (u16*)p;             p += NE * 2;
  u16* Kb  = (u16*)p;             p += NE * 2;
  u16* Vtb = (u16*)p;             p += NE * 2;
  u16* Ab  = Xb;                  // alias: x-cast consumed before attention writes

  prep_kernel<<<5120, 256, 0, stream>>>(x, ctx, Wq, Wk, Wv, Wo,
                                        Xb, Cb, Wqt, Wkt, Wvt, Wot);
  proj_gemm_kernel<<<dim3(64, 8, 3), 256, 0, stream>>>(Xb, Cb, Wqt, Wkt, Wvt,
                                                       bq, bk, bv, Qb, Kb, Vtb);
  attn_kernel<<<1024, 256, 0, stream>>>(Qb, Kb, Vtb, Ab);
  out_gemm_kernel<<<dim3(64, 8), 256, 0, stream>>>(Ab, Wot, bo, out);
}